// Round 3
// baseline (699.320 us; speedup 1.0000x reference)
//
#include <hip/hip_runtime.h>
#include <math.h>

#define D 64
#define K 512
#define TILE_ROWS 256   // 256 rows * 64 floats * 4 B = 64 KB LDS tile
#define P 4             // points per thread (register-blocked)

// ---------------------------------------------------------------------------
// numpy pairwise sum of v[i]*v[i], n=64 — exact numpy algorithm
// ---------------------------------------------------------------------------
__device__ __forceinline__ float np_sumsq64(const float* v)
{
#pragma clang fp contract(off)
    float p[64];
#pragma unroll
    for (int i = 0; i < 64; ++i) p[i] = v[i] * v[i];
    float r[8];
#pragma unroll
    for (int j = 0; j < 8; ++j) r[j] = p[j];
#pragma unroll
    for (int b = 8; b < 64; b += 8) {
#pragma unroll
        for (int j = 0; j < 8; ++j) r[j] += p[b + j];
    }
    return ((r[0] + r[1]) + (r[2] + r[3])) + ((r[4] + r[5]) + (r[6] + r[7]));
}

// ---------------------------------------------------------------------------
// Kernel 1: e2[k] = numpy-f32 sum(e_k*e_k); sq[k] = f32 sqrt(cs[k])
// ---------------------------------------------------------------------------
__global__ void vq_prep(const float* __restrict__ emb,
                        const float* __restrict__ cs,
                        float* __restrict__ e2,
                        float* __restrict__ sq)
{
    int k = blockIdx.x * blockDim.x + threadIdx.x;
    if (k >= K) return;
    float er[64];
    const float* ek = emb + (size_t)k * D;
#pragma unroll
    for (int d = 0; d < 64; ++d) er[d] = ek[d];
    e2[k] = np_sumsq64(er);
    sq[k] = (float)sqrt((double)cs[k]);
}

// ---------------------------------------------------------------------------
// Kernel 2: argmin, numpy-f32 exact, P=4 points per thread.
// Each code float4 read from LDS is reused across 4 points -> 4x fewer
// ds_read_b128 (the R2 bottleneck: LDS issue pipe ~510us at P=1).
// 8 independent fmaf chains (2 rows x 4 points) for ILP at 1 wave/SIMD.
// ---------------------------------------------------------------------------
__global__ __launch_bounds__(256, 1) void vq_argmin(
    const float* __restrict__ x,
    const float* __restrict__ emb,
    const float* __restrict__ e2,
    const float* __restrict__ sq,
    float* __restrict__ out_idx,
    int N)
{
    __shared__ float se[TILE_ROWS * D];   // 64 KB

    int t  = blockIdx.x * blockDim.x + threadIdx.x;
    int n0 = t * P;

    float xr[P][64];
#pragma unroll
    for (int p = 0; p < P; ++p) {
        if (n0 + p < N) {
            const float4* xp = (const float4*)(x + (size_t)(n0 + p) * D);
#pragma unroll
            for (int q = 0; q < 16; ++q) {
                float4 v = xp[q];
                xr[p][4 * q + 0] = v.x;
                xr[p][4 * q + 1] = v.y;
                xr[p][4 * q + 2] = v.z;
                xr[p][4 * q + 3] = v.w;
            }
        } else {
#pragma unroll
            for (int i = 0; i < 64; ++i) xr[p][i] = 0.0f;
        }
    }

    float x2[P];
#pragma unroll
    for (int p = 0; p < P; ++p) x2[p] = np_sumsq64(xr[p]);

    float best[P];
    int   bi[P];
#pragma unroll
    for (int p = 0; p < P; ++p) { best[p] = INFINITY; bi[p] = 0; }

    for (int tt = 0; tt < K / TILE_ROWS; ++tt) {
        __syncthreads();
        {
            const float4* src = (const float4*)(emb + (size_t)tt * TILE_ROWS * D);
            float4* dst = (float4*)se;
            for (int i = threadIdx.x; i < TILE_ROWS * D / 4; i += 256)
                dst[i] = src[i];
        }
        __syncthreads();

        for (int j = 0; j < TILE_ROWS; j += 2) {
            const float* r0 = se + j * D;
            const float* r1 = r0 + D;
            float acc0[P], acc1[P];
#pragma unroll
            for (int p = 0; p < P; ++p) { acc0[p] = 0.0f; acc1[p] = 0.0f; }

#pragma unroll
            for (int k = 0; k < 64; k += 4) {
                float4 u = *(const float4*)(r0 + k);
                float4 w = *(const float4*)(r1 + k);
#pragma unroll
                for (int p = 0; p < P; ++p) {
                    acc0[p] = fmaf(xr[p][k + 0], u.x, acc0[p]);
                    acc0[p] = fmaf(xr[p][k + 1], u.y, acc0[p]);
                    acc0[p] = fmaf(xr[p][k + 2], u.z, acc0[p]);
                    acc0[p] = fmaf(xr[p][k + 3], u.w, acc0[p]);
                    acc1[p] = fmaf(xr[p][k + 0], w.x, acc1[p]);
                    acc1[p] = fmaf(xr[p][k + 1], w.y, acc1[p]);
                    acc1[p] = fmaf(xr[p][k + 2], w.z, acc1[p]);
                    acc1[p] = fmaf(xr[p][k + 3], w.w, acc1[p]);
                }
            }

            int jg = tt * TILE_ROWS + j;
            float q0 = e2[jg], q1 = e2[jg + 1];
            float s0 = sq[jg], s1 = sq[jg + 1];
            {
#pragma clang fp contract(off)
#pragma unroll
                for (int p = 0; p < P; ++p) {
                    float d0 = ((x2[p] + q0) - 2.0f * acc0[p]) * s0;
                    if (d0 < best[p]) { best[p] = d0; bi[p] = jg; }
                    float d1 = ((x2[p] + q1) - 2.0f * acc1[p]) * s1;
                    if (d1 < best[p]) { best[p] = d1; bi[p] = jg + 1; }
                }
            }
        }
    }

#pragma unroll
    for (int p = 0; p < P; ++p)
        if (n0 + p < N) out_idx[n0 + p] = (float)bi[p];
}

// ---------------------------------------------------------------------------
// Kernel 3: gather chosen code, STE output, fp64 per-block loss partials
// ---------------------------------------------------------------------------
__global__ __launch_bounds__(256) void vq_epilogue(
    const float* __restrict__ x,
    const float* __restrict__ emb,
    const float* __restrict__ idx_f,
    float* __restrict__ out_q,
    double* __restrict__ partial)
{
    int i = blockIdx.x * blockDim.x + threadIdx.x;   // float4 index
    int n  = i >> 4;
    int d4 = i & 15;

    int bi = (int)idx_f[n];
    float4 q4 = *(const float4*)(emb + (size_t)bi * D + 4 * d4);
    float4 x4 = ((const float4*)x)[i];

    float4 o;
    o.x = x4.x + (q4.x - x4.x);
    o.y = x4.y + (q4.y - x4.y);
    o.z = x4.z + (q4.z - x4.z);
    o.w = x4.w + (q4.w - x4.w);
    ((float4*)out_q)[i] = o;

    double dx = (double)q4.x - (double)x4.x;
    double dy = (double)q4.y - (double)x4.y;
    double dz = (double)q4.z - (double)x4.z;
    double dw = (double)q4.w - (double)x4.w;
    double s = dx * dx + dy * dy + dz * dz + dw * dw;

#pragma unroll
    for (int off = 32; off > 0; off >>= 1)
        s += __shfl_down(s, off, 64);

    __shared__ double ls[4];
    if ((threadIdx.x & 63) == 0) ls[threadIdx.x >> 6] = s;
    __syncthreads();
    if (threadIdx.x == 0)
        partial[blockIdx.x] = ls[0] + ls[1] + ls[2] + ls[3];
}

// ---------------------------------------------------------------------------
// Kernel 4: reduce partials -> loss
// ---------------------------------------------------------------------------
__global__ __launch_bounds__(256) void vq_finalize(
    const double* __restrict__ partial,
    float* __restrict__ loss_out,
    int nblk, double inv_count)
{
    double s = 0.0;
    for (int i = threadIdx.x; i < nblk; i += 256) s += partial[i];
#pragma unroll
    for (int off = 32; off > 0; off >>= 1)
        s += __shfl_down(s, off, 64);
    __shared__ double ls[4];
    if ((threadIdx.x & 63) == 0) ls[threadIdx.x >> 6] = s;
    __syncthreads();
    if (threadIdx.x == 0) {
        double total = ls[0] + ls[1] + ls[2] + ls[3];
        loss_out[0] = (float)(0.25 * total * inv_count);
    }
}

// ---------------------------------------------------------------------------
extern "C" void kernel_launch(void* const* d_in, const int* in_sizes, int n_in,
                              void* d_out, int out_size, void* d_ws, size_t ws_size,
                              hipStream_t stream)
{
    const float* x   = (const float*)d_in[0];   // [N, 64]
    const float* emb = (const float*)d_in[1];   // [512, 64]
    const float* cs  = (const float*)d_in[2];   // [512]

    const int N = in_sizes[0] / D;              // 262144

    float* out      = (float*)d_out;
    float* out_q    = out;                      // [N*64]
    float* out_loss = out + (size_t)N * D;      // [1]
    float* out_idx  = out_loss + 1;             // [N]

    // workspace layout
    float*  e2      = (float*)d_ws;                       // 512 f32
    float*  sq      = e2 + K;                             // 512 f32
    double* partial = (double*)((char*)d_ws + 8192);      // 16384 f64

    const int nblk_ep = (N * D / 4) / 256;      // 16384
    const int nthreads_argmin = (N + P - 1) / P;          // 65536

    vq_prep<<<(K + 255) / 256, 256, 0, stream>>>(emb, cs, e2, sq);
    vq_argmin<<<(nthreads_argmin + 255) / 256, 256, 0, stream>>>(
        x, emb, e2, sq, out_idx, N);
    vq_epilogue<<<nblk_ep, 256, 0, stream>>>(x, emb, out_idx, out_q, partial);
    vq_finalize<<<1, 256, 0, stream>>>(partial, out_loss, nblk_ep,
                                       1.0 / ((double)N * (double)D));
}

// Round 4
// 473.468 us; speedup vs baseline: 1.4770x; 1.4770x over previous
//
#include <hip/hip_runtime.h>
#include <math.h>

#define D 64
#define K 512
#define P 2             // points per thread (128 VGPRs of x, no spill)

// ---------------------------------------------------------------------------
// numpy pairwise sum of v[i]*v[i], n=64 — exact numpy algorithm
// ---------------------------------------------------------------------------
__device__ __forceinline__ float np_sumsq64(const float* v)
{
#pragma clang fp contract(off)
    float p[64];
#pragma unroll
    for (int i = 0; i < 64; ++i) p[i] = v[i] * v[i];
    float r[8];
#pragma unroll
    for (int j = 0; j < 8; ++j) r[j] = p[j];
#pragma unroll
    for (int b = 8; b < 64; b += 8) {
#pragma unroll
        for (int j = 0; j < 8; ++j) r[j] += p[b + j];
    }
    return ((r[0] + r[1]) + (r[2] + r[3])) + ((r[4] + r[5]) + (r[6] + r[7]));
}

// ---------------------------------------------------------------------------
// Kernel 1: e2[k] = numpy-f32 sum(e_k*e_k); sq[k] = f32 sqrt(cs[k])
// ---------------------------------------------------------------------------
__global__ void vq_prep(const float* __restrict__ emb,
                        const float* __restrict__ cs,
                        float* __restrict__ e2,
                        float* __restrict__ sq)
{
    int k = blockIdx.x * blockDim.x + threadIdx.x;
    if (k >= K) return;
    float er[64];
    const float* ek = emb + (size_t)k * D;
#pragma unroll
    for (int d = 0; d < 64; ++d) er[d] = ek[d];
    e2[k] = np_sumsq64(er);
    sq[k] = (float)sqrt((double)cs[k]);
}

// ---------------------------------------------------------------------------
// Kernel 2 (fused): argmin + gather + STE output + loss partials.
// Codes read straight from global at WAVE-UNIFORM addresses (no LDS):
// compiler can scalarize to s_load (scalar pipe, free) or at worst emits
// broadcast global_load_dwordx4 (~4cyc on VMEM pipe) — either way the R2
// LDS-issue bottleneck (33.5M ds_read_b128 = 510us) is gone.
// Numerics identical to the passing R2 kernel: ascending-k fmaf chain,
// contract-off combine, strict-< ascending-j argmin.
// ---------------------------------------------------------------------------
__global__ __launch_bounds__(256, 1) void vq_main(
    const float* __restrict__ x,
    const float* __restrict__ emb,
    const float* __restrict__ e2,
    const float* __restrict__ sq,
    float* __restrict__ out_q,
    float* __restrict__ out_idx,
    double* __restrict__ partial,
    int N)
{
    int t  = blockIdx.x * blockDim.x + threadIdx.x;
    int n0 = t * P;

    float xr[P][64];
#pragma unroll
    for (int p = 0; p < P; ++p) {
        if (n0 + p < N) {
            const float4* xp = (const float4*)(x + (size_t)(n0 + p) * D);
#pragma unroll
            for (int q = 0; q < 16; ++q) {
                float4 v = xp[q];
                xr[p][4 * q + 0] = v.x;
                xr[p][4 * q + 1] = v.y;
                xr[p][4 * q + 2] = v.z;
                xr[p][4 * q + 3] = v.w;
            }
        } else {
#pragma unroll
            for (int i = 0; i < 64; ++i) xr[p][i] = 0.0f;
        }
    }

    float x2[P];
#pragma unroll
    for (int p = 0; p < P; ++p) x2[p] = np_sumsq64(xr[p]);

    float best[P];
    int   bi[P];
#pragma unroll
    for (int p = 0; p < P; ++p) { best[p] = INFINITY; bi[p] = 0; }

    const float4* eb = (const float4*)emb;

    for (int j = 0; j < K; j += 2) {
        const float4* r0 = eb + (size_t)j * 16;
        const float4* r1 = r0 + 16;

        float acc0[P], acc1[P];
#pragma unroll
        for (int p = 0; p < P; ++p) { acc0[p] = 0.0f; acc1[p] = 0.0f; }

#pragma unroll
        for (int k4 = 0; k4 < 16; ++k4) {
            float4 u = r0[k4];
            float4 w = r1[k4];
            int k = 4 * k4;
#pragma unroll
            for (int p = 0; p < P; ++p) {
                acc0[p] = fmaf(xr[p][k + 0], u.x, acc0[p]);
                acc0[p] = fmaf(xr[p][k + 1], u.y, acc0[p]);
                acc0[p] = fmaf(xr[p][k + 2], u.z, acc0[p]);
                acc0[p] = fmaf(xr[p][k + 3], u.w, acc0[p]);
                acc1[p] = fmaf(xr[p][k + 0], w.x, acc1[p]);
                acc1[p] = fmaf(xr[p][k + 1], w.y, acc1[p]);
                acc1[p] = fmaf(xr[p][k + 2], w.z, acc1[p]);
                acc1[p] = fmaf(xr[p][k + 3], w.w, acc1[p]);
            }
        }

        float q0 = e2[j], q1 = e2[j + 1];
        float s0 = sq[j], s1 = sq[j + 1];
        {
#pragma clang fp contract(off)
#pragma unroll
            for (int p = 0; p < P; ++p) {
                float d0 = ((x2[p] + q0) - 2.0f * acc0[p]) * s0;
                if (d0 < best[p]) { best[p] = d0; bi[p] = j; }
                float d1 = ((x2[p] + q1) - 2.0f * acc1[p]) * s1;
                if (d1 < best[p]) { best[p] = d1; bi[p] = j + 1; }
            }
        }
    }

    // ---- fused epilogue: index write, gather, STE output, loss partial ----
    double s = 0.0;
#pragma unroll
    for (int p = 0; p < P; ++p) {
        if (n0 + p >= N) continue;
        out_idx[n0 + p] = (float)bi[p];
        const float4* qr = (const float4*)(emb + (size_t)bi[p] * D);
        float4* oq = (float4*)(out_q + (size_t)(n0 + p) * D);
#pragma unroll
        for (int q = 0; q < 16; ++q) {
            float4 q4 = qr[q];
            float xa = xr[p][4 * q + 0], xb = xr[p][4 * q + 1];
            float xc = xr[p][4 * q + 2], xd = xr[p][4 * q + 3];
            float4 o;
            {
#pragma clang fp contract(off)
                o.x = xa + (q4.x - xa);
                o.y = xb + (q4.y - xb);
                o.z = xc + (q4.z - xc);
                o.w = xd + (q4.w - xd);
            }
            oq[q] = o;
            double dx = (double)q4.x - (double)xa;
            double dy = (double)q4.y - (double)xb;
            double dz = (double)q4.z - (double)xc;
            double dw = (double)q4.w - (double)xd;
            s += dx * dx + dy * dy + dz * dz + dw * dw;
        }
    }

#pragma unroll
    for (int off = 32; off > 0; off >>= 1)
        s += __shfl_down(s, off, 64);

    __shared__ double ls[4];
    if ((threadIdx.x & 63) == 0) ls[threadIdx.x >> 6] = s;
    __syncthreads();
    if (threadIdx.x == 0)
        partial[blockIdx.x] = ls[0] + ls[1] + ls[2] + ls[3];
}

// ---------------------------------------------------------------------------
// Kernel 3: reduce partials -> loss
// ---------------------------------------------------------------------------
__global__ __launch_bounds__(256) void vq_finalize(
    const double* __restrict__ partial,
    float* __restrict__ loss_out,
    int nblk, double inv_count)
{
    double s = 0.0;
    for (int i = threadIdx.x; i < nblk; i += 256) s += partial[i];
#pragma unroll
    for (int off = 32; off > 0; off >>= 1)
        s += __shfl_down(s, off, 64);
    __shared__ double ls[4];
    if ((threadIdx.x & 63) == 0) ls[threadIdx.x >> 6] = s;
    __syncthreads();
    if (threadIdx.x == 0) {
        double total = ls[0] + ls[1] + ls[2] + ls[3];
        loss_out[0] = (float)(0.25 * total * inv_count);
    }
}

// ---------------------------------------------------------------------------
extern "C" void kernel_launch(void* const* d_in, const int* in_sizes, int n_in,
                              void* d_out, int out_size, void* d_ws, size_t ws_size,
                              hipStream_t stream)
{
    const float* x   = (const float*)d_in[0];   // [N, 64]
    const float* emb = (const float*)d_in[1];   // [512, 64]
    const float* cs  = (const float*)d_in[2];   // [512]

    const int N = in_sizes[0] / D;              // 262144

    float* out      = (float*)d_out;
    float* out_q    = out;                      // [N*64]
    float* out_loss = out + (size_t)N * D;      // [1]
    float* out_idx  = out_loss + 1;             // [N]

    // workspace layout
    float*  e2      = (float*)d_ws;                       // 512 f32
    float*  sq      = e2 + K;                             // 512 f32
    double* partial = (double*)((char*)d_ws + 8192);      // per-block f64

    const int nthreads = (N + P - 1) / P;                 // 131072
    const int nblk     = (nthreads + 255) / 256;          // 512

    vq_prep<<<(K + 255) / 256, 256, 0, stream>>>(emb, cs, e2, sq);
    vq_main<<<nblk, 256, 0, stream>>>(x, emb, e2, sq,
                                      out_q, out_idx, partial, N);
    vq_finalize<<<1, 256, 0, stream>>>(partial, out_loss, nblk,
                                       1.0 / ((double)N * (double)D));
}